// Round 11
// baseline (296.611 us; speedup 1.0000x reference)
//
#include <hip/hip_runtime.h>

// ---------------- problem constants ----------------
#define LSEQ   16384        // H*W
#define BLROWS 65536        // B * L
#define DM     256          // d_model
#define DI     512          // d_inner
#define DXZ    1024         // 2 * d_inner

// GEMM1 tile
#define BM 128
#define BN 128
#define BK 32

typedef __attribute__((ext_vector_type(8))) short s16x8;
typedef __attribute__((ext_vector_type(4))) short s16x4;
typedef __attribute__((ext_vector_type(4))) float f32x4;

__device__ __forceinline__ float bf2f(unsigned short h) {
  union { unsigned u; float f; } c; c.u = ((unsigned)h) << 16; return c.f;
}
__device__ __forceinline__ unsigned short f2bf(float f) {
  union { float f; unsigned u; } c; c.f = f;
  unsigned u = c.u;
  return (unsigned short)((u + 0x7fffu + ((u >> 16) & 1u)) >> 16);
}

// ---------------- fp32 -> bf16 convert ----------------
__global__ __launch_bounds__(256)
void cvt_f32_bf16(const float* __restrict__ src, unsigned short* __restrict__ dst, int n4) {
  for (int i = blockIdx.x * blockDim.x + threadIdx.x; i < n4; i += gridDim.x * blockDim.x) {
    const float4 v = reinterpret_cast<const float4*>(src)[i];
    s16x4 o;
    o[0] = (short)f2bf(v.x);
    o[1] = (short)f2bf(v.y);
    o[2] = (short)f2bf(v.z);
    o[3] = (short)f2bf(v.w);
    reinterpret_cast<s16x4*>(dst)[i] = o;
  }
}

// ---------------- async global->LDS (16B per lane) ----------------
__device__ __forceinline__ void gload16(const void* g, void* l) {
  __builtin_amdgcn_global_load_lds((__attribute__((address_space(1))) void*)(g),
                                   (__attribute__((address_space(3))) void*)(l),
                                   16, 0, 0);
}

// ============================================================================
// Fused GEMM1 + depthwise causal conv(K=4) + bias + SiLU + gate.  (verified r9)
// ============================================================================
__global__ __launch_bounds__(256, 4)
void gemm1_conv(const unsigned short* __restrict__ A,
                const unsigned short* __restrict__ Bw,
                const float* __restrict__ cw,    // [512][4]
                const float* __restrict__ cb,    // [512]
                unsigned short* __restrict__ Y) {
  __shared__ unsigned short lds[2][BM * BK + BN * BK];   // 32 KB staging
  __shared__ float patch[2][3][64];                       // seam rows

  const int tid  = threadIdx.x;
  const int lane = tid & 63;
  const int w    = tid >> 6;
  const int wr2  = w >> 1;          // 0..1 : row half (64 rows)
  const int wcol = w & 1;           // 0..1 : channel half (32 ch)
  const int g    = lane >> 4;       // quarter-group
  const int c0   = lane & 15;
  const int m0   = blockIdx.y * BM;
  const int n0x  = blockIdx.x * 64; // x-channel base (0..448)

  const int srow = tid >> 2;        // 0..63
  const int scol = (tid & 3) * 8;   // 0,8,16,24

  f32x4 ax[4][2], az[4][2];
#pragma unroll
  for (int i = 0; i < 4; ++i)
#pragma unroll
    for (int j = 0; j < 2; ++j)
#pragma unroll
      for (int r = 0; r < 4; ++r) { ax[i][j][r] = 0.f; az[i][j][r] = 0.f; }

  auto stage = [&](int ks, int buf) {
    const unsigned short* Ag = A + (size_t)(m0 + srow) * DM + ks * BK + scol;
    unsigned short* lA = &lds[buf][0]       + tid * 8;
    unsigned short* lB = &lds[buf][BM * BK] + tid * 8;
#pragma unroll
    for (int i = 0; i < 2; ++i) {
      gload16(Ag + (size_t)(i * 64) * DM, lA + i * 2048);
      const int lr   = srow + i * 64;                            // local B row 0..127
      const int grow = (i == 0) ? (n0x + lr) : (448 + n0x + lr); // x rows / z rows
      gload16(Bw + (size_t)grow * DM + ks * BK + scol, lB + i * 2048);
    }
  };

  stage(0, 0);

  const int kSteps = DM / BK;   // 8
  for (int ks = 0; ks < kSteps; ++ks) {
    const int cur = ks & 1;
    __syncthreads();
    if (ks + 1 < kSteps) stage(ks + 1, cur ^ 1);

    const unsigned short* lA = &lds[cur][0];
    const unsigned short* lB = &lds[cur][BM * BK];
    const int lrow = lane & 15;
    const int lk   = g * 8;
    s16x8 af[4], bx[2], bz[2];
#pragma unroll
    for (int i = 0; i < 4; ++i)
      af[i] = *(const s16x8*)(lA + (wr2 * 64 + i * 16 + lrow) * BK + lk);
#pragma unroll
    for (int j = 0; j < 2; ++j) {
      bx[j] = *(const s16x8*)(lB + (wcol * 32 + j * 16 + lrow) * BK + lk);
      bz[j] = *(const s16x8*)(lB + (64 + wcol * 32 + j * 16 + lrow) * BK + lk);
    }
#pragma unroll
    for (int i = 0; i < 4; ++i)
#pragma unroll
      for (int j = 0; j < 2; ++j) {
        ax[i][j] = __builtin_amdgcn_mfma_f32_16x16x32_bf16(af[i], bx[j], ax[i][j], 0, 0, 0);
        az[i][j] = __builtin_amdgcn_mfma_f32_16x16x32_bf16(af[i], bz[j], az[i][j], 0, 0, 0);
      }
  }

  // ---------------- register-resident epilogue ----------------
  if (wr2 == 0 && g == 3) {
#pragma unroll
    for (int j = 0; j < 2; ++j) {
      const int chl = wcol * 32 + j * 16 + c0;
      patch[1][0][chl] = ax[3][j][1];   // row 61
      patch[1][1][chl] = ax[3][j][2];   // row 62
      patch[1][2][chl] = ax[3][j][3];   // row 63
    }
  }
  if (tid < 192) {
    const int hi = tid >> 6;       // 0..2
    const int hc = tid & 63;       // 0..63
    float s = 0.f;
    if ((m0 & (LSEQ - 1)) != 0) {
      const unsigned short* xr  = A  + (size_t)(m0 - 3 + hi) * DM;
      const unsigned short* wr_ = Bw + (size_t)(n0x + hc) * DM;
#pragma unroll
      for (int kk = 0; kk < DM; kk += 8) {
        const s16x8 xa = *(const s16x8*)(xr + kk);
        const s16x8 wa = *(const s16x8*)(wr_ + kk);
#pragma unroll
        for (int jj = 0; jj < 8; ++jj)
          s += bf2f((unsigned short)xa[jj]) * bf2f((unsigned short)wa[jj]);
      }
    }
    patch[0][hi][hc] = s;
  }
  __syncthreads();

  const int src = (lane - 16) & 63;
#pragma unroll
  for (int j = 0; j < 2; ++j) {
    const int chl = wcol * 32 + j * 16 + c0;
    const int ch  = n0x + chl;
    const float4 w4 = *(const float4*)(cw + (size_t)ch * 4);
    const float cbv = cb[ch];
#pragma unroll
    for (int i = 0; i < 4; ++i) {
      const f32x4 curf = ax[i][j];
      const f32x4 prvf = (i > 0) ? ax[(i > 0 ? i - 1 : 0)][j] : ax[0][j];
      const float s1 = (g == 3) ? prvf[1] : curf[1];
      const float s2 = (g == 3) ? prvf[2] : curf[2];
      const float s3 = (g == 3) ? prvf[3] : curf[3];
      float vm3 = __shfl(s1, src);
      float vm2 = __shfl(s2, src);
      float vm1 = __shfl(s3, src);
      if (i == 0 && g == 0) {
        vm3 = patch[wr2][0][chl];
        vm2 = patch[wr2][1][chl];
        vm1 = patch[wr2][2][chl];
      }
      const float vv[7] = {vm3, vm2, vm1, curf[0], curf[1], curf[2], curf[3]};
      const int mbase = m0 + wr2 * 64 + i * 16 + g * 4;
#pragma unroll
      for (int r = 0; r < 4; ++r) {
        float a = cbv + w4.x * vv[r] + w4.y * vv[r + 1] + w4.z * vv[r + 2] + w4.w * vv[r + 3];
        const float su = a * __builtin_amdgcn_rcpf(1.f + __expf(-a));
        const float z  = az[i][j][r];
        const float sz = z * __builtin_amdgcn_rcpf(1.f + __expf(-z));
        Y[(size_t)(mbase + r) * DI + ch] = f2bf(4.f * su * sz);
      }
    }
  }
}

// ============================================================================
// GEMM2, LDS-free / barrier-free: out[M,256] = y[M,512] @ W_out[256,512]^T.
// A-frags from L3-resident y, B-frags from L2-resident W_out; regs only.
// grid = (256/128, M/128), 256 threads.
// ============================================================================
__global__ __launch_bounds__(256)
void gemm2_direct(const unsigned short* __restrict__ A,   // y_bf [M,512]
                  const unsigned short* __restrict__ B,   // wout_bf [256,512]
                  float* __restrict__ C) {
  const int tid  = threadIdx.x;
  const int lane = tid & 63;
  const int wv   = tid >> 6;
  const int wr   = wv >> 1;
  const int wc   = wv & 1;
  const int m0   = blockIdx.y * 128;
  const int n0   = blockIdx.x * 128;
  const int lrow = lane & 15;
  const int lk0  = (lane >> 4) * 8;

  f32x4 acc[4][4];
#pragma unroll
  for (int i = 0; i < 4; ++i)
#pragma unroll
    for (int j = 0; j < 4; ++j)
#pragma unroll
      for (int r = 0; r < 4; ++r) acc[i][j][r] = 0.f;

  const unsigned short* ap[4];
  const unsigned short* bp[4];
#pragma unroll
  for (int i = 0; i < 4; ++i)
    ap[i] = A + (size_t)(m0 + wr * 64 + i * 16 + lrow) * DI + lk0;
#pragma unroll
  for (int j = 0; j < 4; ++j)
    bp[j] = B + (size_t)(n0 + wc * 64 + j * 16 + lrow) * DI + lk0;

#pragma unroll
  for (int ks = 0; ks < 16; ++ks) {
    s16x8 af[4], bf[4];
#pragma unroll
    for (int i = 0; i < 4; ++i) af[i] = *(const s16x8*)(ap[i] + ks * 32);
#pragma unroll
    for (int j = 0; j < 4; ++j) bf[j] = *(const s16x8*)(bp[j] + ks * 32);
#pragma unroll
    for (int i = 0; i < 4; ++i)
#pragma unroll
      for (int j = 0; j < 4; ++j)
        acc[i][j] = __builtin_amdgcn_mfma_f32_16x16x32_bf16(af[i], bf[j], acc[i][j], 0, 0, 0);
  }

  const int r0 = (lane >> 4) * 4;
  const int c0 = lane & 15;
#pragma unroll
  for (int i = 0; i < 4; ++i)
#pragma unroll
    for (int j = 0; j < 4; ++j) {
      const int rr = m0 + wr * 64 + i * 16 + r0;
      const int cc = n0 + wc * 64 + j * 16 + c0;
#pragma unroll
      for (int r = 0; r < 4; ++r)
        C[(size_t)(rr + r) * DM + cc] = acc[i][j][r];
    }
}

// ---------------- launch ----------------
extern "C" void kernel_launch(void* const* d_in, const int* in_sizes, int n_in,
                              void* d_out, int out_size, void* d_ws, size_t ws_size,
                              hipStream_t stream) {
  const float* x      = (const float*)d_in[0];
  const float* W_in   = (const float*)d_in[1];
  const float* conv_w = (const float*)d_in[2];
  const float* conv_b = (const float*)d_in[3];
  const float* W_out  = (const float*)d_in[4];

  char* ws = (char*)d_ws;
  unsigned short* y_bf    = (unsigned short*)(ws);                  // 64 MiB
  unsigned short* x_bf    = (unsigned short*)(ws + (64ull << 20));  // 32 MiB
  unsigned short* win_bf  = (unsigned short*)(ws + (100ull << 20));
  unsigned short* wout_bf = (unsigned short*)(ws + (101ull << 20));

  // 1) convert inputs to bf16
  cvt_f32_bf16<<<2048, 256, 0, stream>>>(x,     x_bf,    (BLROWS * DM) / 4);
  cvt_f32_bf16<<<256,  256, 0, stream>>>(W_in,  win_bf,  (DXZ * DM) / 4);
  cvt_f32_bf16<<<128,  256, 0, stream>>>(W_out, wout_bf, (DM * DI) / 4);

  // 2) fused: y = 4*silu(conv(x@W_in_x^T))*silu(x@W_in_z^T)   (65536 x 512)
  gemm1_conv<<<dim3(DI / 64, BLROWS / BM), 256, 0, stream>>>(
      x_bf, win_bf, conv_w, conv_b, y_bf);

  // 3) out = y @ W_out^T (65536 x 256, K=512), fp32 out — LDS/barrier-free
  gemm2_direct<<<dim3(DM / 128, BLROWS / 128), 256, 0, stream>>>(
      y_bf, wout_bf, (float*)d_out);
}

// Round 12
// 283.592 us; speedup vs baseline: 1.0459x; 1.0459x over previous
//
#include <hip/hip_runtime.h>

// ---------------- problem constants ----------------
#define LSEQ   16384        // H*W
#define BLROWS 65536        // B * L
#define DM     256          // d_model
#define DI     512          // d_inner
#define DXZ    1024         // 2 * d_inner

// GEMM tile
#define BM 128
#define BN 128
#define BK 32

typedef __attribute__((ext_vector_type(8))) short s16x8;
typedef __attribute__((ext_vector_type(4))) short s16x4;
typedef __attribute__((ext_vector_type(4))) float f32x4;

__device__ __forceinline__ float bf2f(unsigned short h) {
  union { unsigned u; float f; } c; c.u = ((unsigned)h) << 16; return c.f;
}
__device__ __forceinline__ unsigned short f2bf(float f) {
  union { float f; unsigned u; } c; c.f = f;
  unsigned u = c.u;
  return (unsigned short)((u + 0x7fffu + ((u >> 16) & 1u)) >> 16);
}

// ---------------- fp32 -> bf16 convert (weights only now) ----------------
__global__ __launch_bounds__(256)
void cvt_f32_bf16(const float* __restrict__ src, unsigned short* __restrict__ dst, int n4) {
  for (int i = blockIdx.x * blockDim.x + threadIdx.x; i < n4; i += gridDim.x * blockDim.x) {
    const float4 v = reinterpret_cast<const float4*>(src)[i];
    s16x4 o;
    o[0] = (short)f2bf(v.x);
    o[1] = (short)f2bf(v.y);
    o[2] = (short)f2bf(v.z);
    o[3] = (short)f2bf(v.w);
    reinterpret_cast<s16x4*>(dst)[i] = o;
  }
}

// ---------------- async global->LDS (16B per lane) ----------------
__device__ __forceinline__ void gload16(const void* g, void* l) {
  __builtin_amdgcn_global_load_lds((__attribute__((address_space(1))) void*)(g),
                                   (__attribute__((address_space(3))) void*)(l),
                                   16, 0, 0);
}

// ============================================================================
// Fused GEMM1 + depthwise causal conv(K=4) + bias + SiLU + gate.
// r12: A-staging reads fp32 x directly and converts in-register (kills cvt_x).
//   X  = x      [65536, 256] fp32
//   Bw = win_bf [1024, 256]  bf16 (rows 0..511 = x-branch, 512..1023 = z-branch)
//   Y  = y_bf   [65536, 512] bf16
// grid = (512/64, 65536/128); LDS 32KB staging + patch -> 4 blocks/CU
// ============================================================================
__global__ __launch_bounds__(256, 4)
void gemm1_conv(const float* __restrict__ X,
                const unsigned short* __restrict__ Bw,
                const float* __restrict__ cw,    // [512][4]
                const float* __restrict__ cb,    // [512]
                unsigned short* __restrict__ Y) {
  __shared__ unsigned short lds[2][BM * BK + BN * BK];   // 32 KB staging
  __shared__ float patch[2][3][64];                       // seam rows

  const int tid  = threadIdx.x;
  const int lane = tid & 63;
  const int w    = tid >> 6;
  const int wr2  = w >> 1;          // 0..1 : row half (64 rows)
  const int wcol = w & 1;           // 0..1 : channel half (32 ch)
  const int g    = lane >> 4;       // quarter-group
  const int c0   = lane & 15;
  const int m0   = blockIdx.y * BM;
  const int n0x  = blockIdx.x * 64; // x-channel base (0..448)

  const int srow = tid >> 2;        // 0..63  (B staging)
  const int scol = (tid & 3) * 8;   // 0,8,16,24

  // A reg-staging decomposition: idx = i*256+tid; row = idx>>3, c4 = idx&7
  const int arow0 = tid >> 3;       // +i*32
  const int ac4   = tid & 7;

  f32x4 ax[4][2], az[4][2];
#pragma unroll
  for (int i = 0; i < 4; ++i)
#pragma unroll
    for (int j = 0; j < 2; ++j)
#pragma unroll
      for (int r = 0; r < 4; ++r) { ax[i][j][r] = 0.f; az[i][j][r] = 0.f; }

  float4 areg[4];
  auto loadA = [&](int ks) {
#pragma unroll
    for (int i = 0; i < 4; ++i)
      areg[i] = *(const float4*)(X + (size_t)(m0 + arow0 + i * 32) * DM + ks * BK + ac4 * 4);
  };
  auto writeA = [&](int buf) {
#pragma unroll
    for (int i = 0; i < 4; ++i) {
      s16x4 o;
      o[0] = (short)f2bf(areg[i].x);
      o[1] = (short)f2bf(areg[i].y);
      o[2] = (short)f2bf(areg[i].z);
      o[3] = (short)f2bf(areg[i].w);
      *(s16x4*)(&lds[buf][0] + (arow0 + i * 32) * BK + ac4 * 4) = o;
    }
  };
  auto stageB = [&](int ks, int buf) {
    unsigned short* lB = &lds[buf][BM * BK] + tid * 8;
#pragma unroll
    for (int i = 0; i < 2; ++i) {
      const int lr   = srow + i * 64;                            // local B row 0..127
      const int grow = (i == 0) ? (n0x + lr) : (448 + n0x + lr); // x rows / z rows
      gload16(Bw + (size_t)grow * DM + ks * BK + scol, lB + i * 2048);
    }
  };

  // prologue: stage tile 0
  loadA(0);
  writeA(0);
  stageB(0, 0);

  const int kSteps = DM / BK;   // 8
  for (int ks = 0; ks < kSteps; ++ks) {
    const int cur = ks & 1;
    __syncthreads();                 // drains prev A ds_writes + B gload_lds: buf cur ready
    if (ks + 1 < kSteps) {
      loadA(ks + 1);                 // async fp32 loads, land during MFMA phase
      stageB(ks + 1, cur ^ 1);       // async gload_lds
    }

    const unsigned short* lA = &lds[cur][0];
    const unsigned short* lB = &lds[cur][BM * BK];
    const int lrow = lane & 15;
    const int lk   = g * 8;
    s16x8 af[4], bx[2], bz[2];
#pragma unroll
    for (int i = 0; i < 4; ++i)
      af[i] = *(const s16x8*)(lA + (wr2 * 64 + i * 16 + lrow) * BK + lk);
#pragma unroll
    for (int j = 0; j < 2; ++j) {
      bx[j] = *(const s16x8*)(lB + (wcol * 32 + j * 16 + lrow) * BK + lk);
      bz[j] = *(const s16x8*)(lB + (64 + wcol * 32 + j * 16 + lrow) * BK + lk);
    }
#pragma unroll
    for (int i = 0; i < 4; ++i)
#pragma unroll
      for (int j = 0; j < 2; ++j) {
        ax[i][j] = __builtin_amdgcn_mfma_f32_16x16x32_bf16(af[i], bx[j], ax[i][j], 0, 0, 0);
        az[i][j] = __builtin_amdgcn_mfma_f32_16x16x32_bf16(af[i], bz[j], az[i][j], 0, 0, 0);
      }

    if (ks + 1 < kSteps) writeA(cur ^ 1);   // cvt + ds_write after compute (latency hidden)
  }

  // ---------------- register-resident epilogue ----------------
  if (wr2 == 0 && g == 3) {
#pragma unroll
    for (int j = 0; j < 2; ++j) {
      const int chl = wcol * 32 + j * 16 + c0;
      patch[1][0][chl] = ax[3][j][1];   // row 61
      patch[1][1][chl] = ax[3][j][2];   // row 62
      patch[1][2][chl] = ax[3][j][3];   // row 63
    }
  }
  // block halo rows m0-3..m0-1 (x-branch pre-activation), fp32 x re-quantized to bf16
  if (tid < 192) {
    const int hi = tid >> 6;       // 0..2
    const int hc = tid & 63;       // 0..63
    float s = 0.f;
    if ((m0 & (LSEQ - 1)) != 0) {
      const float*          xr  = X  + (size_t)(m0 - 3 + hi) * DM;
      const unsigned short* wr_ = Bw + (size_t)(n0x + hc) * DM;
#pragma unroll
      for (int kk = 0; kk < DM; kk += 4) {
        const float4 xa = *(const float4*)(xr + kk);
        const s16x4  wa = *(const s16x4*)(wr_ + kk);
        s += bf2f(f2bf(xa.x)) * bf2f((unsigned short)wa[0]);
        s += bf2f(f2bf(xa.y)) * bf2f((unsigned short)wa[1]);
        s += bf2f(f2bf(xa.z)) * bf2f((unsigned short)wa[2]);
        s += bf2f(f2bf(xa.w)) * bf2f((unsigned short)wa[3]);
      }
    }
    patch[0][hi][hc] = s;
  }
  __syncthreads();

  const int src = (lane - 16) & 63;
#pragma unroll
  for (int j = 0; j < 2; ++j) {
    const int chl = wcol * 32 + j * 16 + c0;
    const int ch  = n0x + chl;
    const float4 w4 = *(const float4*)(cw + (size_t)ch * 4);
    const float cbv = cb[ch];
#pragma unroll
    for (int i = 0; i < 4; ++i) {
      const f32x4 curf = ax[i][j];
      const f32x4 prvf = (i > 0) ? ax[(i > 0 ? i - 1 : 0)][j] : ax[0][j];
      const float s1 = (g == 3) ? prvf[1] : curf[1];
      const float s2 = (g == 3) ? prvf[2] : curf[2];
      const float s3 = (g == 3) ? prvf[3] : curf[3];
      float vm3 = __shfl(s1, src);
      float vm2 = __shfl(s2, src);
      float vm1 = __shfl(s3, src);
      if (i == 0 && g == 0) {
        vm3 = patch[wr2][0][chl];
        vm2 = patch[wr2][1][chl];
        vm1 = patch[wr2][2][chl];
      }
      const float vv[7] = {vm3, vm2, vm1, curf[0], curf[1], curf[2], curf[3]};
      const int mbase = m0 + wr2 * 64 + i * 16 + g * 4;
#pragma unroll
      for (int r = 0; r < 4; ++r) {
        float a = cbv + w4.x * vv[r] + w4.y * vv[r + 1] + w4.z * vv[r + 2] + w4.w * vv[r + 3];
        const float su = a * __builtin_amdgcn_rcpf(1.f + __expf(-a));
        const float z  = az[i][j][r];
        const float sz = z * __builtin_amdgcn_rcpf(1.f + __expf(-z));
        Y[(size_t)(mbase + r) * DI + ch] = f2bf(4.f * su * sz);
      }
    }
  }
}

// ---------------- bf16 GEMM: C[M,N] = A[M,K] @ B[N,K]^T, fp32 out ----------
// (r9-verified staged version, BK=32, 4 blocks/CU)
__global__ __launch_bounds__(256, 4)
void gemm_bt_f32(const unsigned short* __restrict__ A,
                 const unsigned short* __restrict__ B,
                 float* __restrict__ C,
                 int M, int N, int K) {
  __shared__ unsigned short lds[2][BM * BK + BN * BK];   // 32 KB

  const int tid  = threadIdx.x;
  const int lane = tid & 63;
  const int wv   = tid >> 6;
  const int wr   = wv >> 1;
  const int wc   = wv & 1;
  const int m0   = blockIdx.y * BM;
  const int n0   = blockIdx.x * BN;

  const int srow = tid >> 2;        // 0..63
  const int scol = (tid & 3) * 8;   // 0,8,16,24

  const int kSteps = K / BK;

  f32x4 acc[4][4];
#pragma unroll
  for (int i = 0; i < 4; ++i)
#pragma unroll
    for (int j = 0; j < 4; ++j)
#pragma unroll
      for (int r = 0; r < 4; ++r) acc[i][j][r] = 0.f;

  auto stage = [&](int ks, int buf) {
    const unsigned short* Ag = A + (size_t)(m0 + srow) * K + ks * BK + scol;
    const unsigned short* Bg = B + (size_t)(n0 + srow) * K + ks * BK + scol;
    unsigned short* lA = &lds[buf][0]       + tid * 8;
    unsigned short* lB = &lds[buf][BM * BK] + tid * 8;
#pragma unroll
    for (int i = 0; i < 2; ++i) {
      gload16(Ag + (size_t)(i * 64) * K, lA + i * 2048);
      gload16(Bg + (size_t)(i * 64) * K, lB + i * 2048);
    }
  };

  stage(0, 0);

  for (int ks = 0; ks < kSteps; ++ks) {
    const int cur = ks & 1;
    __syncthreads();
    if (ks + 1 < kSteps) stage(ks + 1, cur ^ 1);

    const unsigned short* lA = &lds[cur][0];
    const unsigned short* lB = &lds[cur][BM * BK];
    const int lrow = lane & 15;
    const int lk   = (lane >> 4) * 8;
    s16x8 af[4], bf[4];
#pragma unroll
    for (int i = 0; i < 4; ++i)
      af[i] = *(const s16x8*)(lA + (wr * 64 + i * 16 + lrow) * BK + lk);
#pragma unroll
    for (int j = 0; j < 4; ++j)
      bf[j] = *(const s16x8*)(lB + (wc * 64 + j * 16 + lrow) * BK + lk);
#pragma unroll
    for (int i = 0; i < 4; ++i)
#pragma unroll
      for (int j = 0; j < 4; ++j)
        acc[i][j] = __builtin_amdgcn_mfma_f32_16x16x32_bf16(af[i], bf[j], acc[i][j], 0, 0, 0);
  }

  const int r0 = (lane >> 4) * 4;
  const int c0 = lane & 15;
#pragma unroll
  for (int i = 0; i < 4; ++i)
#pragma unroll
    for (int j = 0; j < 4; ++j) {
      const int rr = m0 + wr * 64 + i * 16 + r0;
      const int cc = n0 + wc * 64 + j * 16 + c0;
#pragma unroll
      for (int r = 0; r < 4; ++r)
        C[(size_t)(rr + r) * N + cc] = acc[i][j][r];
    }
}

// ---------------- launch ----------------
extern "C" void kernel_launch(void* const* d_in, const int* in_sizes, int n_in,
                              void* d_out, int out_size, void* d_ws, size_t ws_size,
                              hipStream_t stream) {
  const float* x      = (const float*)d_in[0];
  const float* W_in   = (const float*)d_in[1];
  const float* conv_w = (const float*)d_in[2];
  const float* conv_b = (const float*)d_in[3];
  const float* W_out  = (const float*)d_in[4];

  char* ws = (char*)d_ws;
  unsigned short* y_bf    = (unsigned short*)(ws);                  // 64 MiB
  unsigned short* win_bf  = (unsigned short*)(ws + (100ull << 20));
  unsigned short* wout_bf = (unsigned short*)(ws + (101ull << 20));

  // 1) convert weights to bf16 (x is converted in-kernel now)
  cvt_f32_bf16<<<256, 256, 0, stream>>>(W_in,  win_bf,  (DXZ * DM) / 4);
  cvt_f32_bf16<<<128, 256, 0, stream>>>(W_out, wout_bf, (DM * DI) / 4);

  // 2) fused: y = 4*silu(conv(x@W_in_x^T))*silu(x@W_in_z^T)   (65536 x 512)
  gemm1_conv<<<dim3(DI / 64, BLROWS / BM), 256, 0, stream>>>(
      x, win_bf, conv_w, conv_b, y_bf);

  // 3) out = y @ W_out^T (65536 x 256, K=512), fp32 out
  gemm_bt_f32<<<dim3(DM / BN, BLROWS / BM), 256, 0, stream>>>(
      y_bf, wout_bf, (float*)d_out, BLROWS, DM, DI);
}